// Round 3
// baseline (301.789 us; speedup 1.0000x reference)
//
#include <hip/hip_runtime.h>
#include <hip/hip_bf16.h>
#include <stdint.h>
#include <stddef.h>

#define Bb 256
#define Mm 128
#define Ee 512
#define Vv 32000
#define E3 1536
#define MS ((size_t)Bb * Mm * Ee)

typedef __attribute__((ext_vector_type(8))) short bf16x8;
typedef __attribute__((ext_vector_type(4))) float f32x4;

__device__ __forceinline__ float bf2f(unsigned short u) {
  union { unsigned int i; float f; } v; v.i = ((unsigned int)u) << 16; return v.f;
}
__device__ __forceinline__ unsigned int f2bf(float f) {
  union { float f; unsigned int u; } v; v.f = f;
  unsigned int u = v.u;
  return ((u + 0x7fffu + ((u >> 16) & 1u)) >> 16);
}

// all 3 fp32 tables -> interleaved bf16 table tabI[v][t][512]
__global__ void convert3_kernel(const float* __restrict__ A0, const float* __restrict__ A1,
                                const float* __restrict__ A2,
                                unsigned short* __restrict__ tabI) {
  const size_t NG = (size_t)Vv * 192;  // groups of 8 elems: v * (3 tables * 64 cols)
  for (size_t g = (size_t)blockIdx.x * blockDim.x + threadIdx.x; g < NG;
       g += (size_t)gridDim.x * blockDim.x) {
    const size_t v = g / 192;
    const int rem = (int)(g - v * 192);
    const int t = rem >> 6, c = rem & 63;
    const float* src = (t == 0 ? A0 : t == 1 ? A1 : A2) + v * Ee + c * 8;
    float4 f0 = *(const float4*)src;
    float4 f1 = *(const float4*)(src + 4);
    unsigned int o[4];
    o[0] = f2bf(f0.x) | (f2bf(f0.y) << 16);
    o[1] = f2bf(f0.z) | (f2bf(f0.w) << 16);
    o[2] = f2bf(f1.x) | (f2bf(f1.y) << 16);
    o[3] = f2bf(f1.z) | (f2bf(f1.w) << 16);
    *(uint4*)(tabI + (v * 3 + t) * Ee + (size_t)c * 8) = *(uint4*)o;
  }
}

// mem[t][bm][:] = sum_k tabI[ctx[bm,k]][t][:]  ; 64 thr/block, 2 bm per block
__global__ __launch_bounds__(64) void gather3_kernel(const int* __restrict__ ctx,
                                                     const unsigned short* __restrict__ tabI,
                                                     unsigned short* __restrict__ mem) {
  const int bm0 = blockIdx.x;  // 0..16383
  const int e = threadIdx.x * 8;
  const int4 ca = *(const int4*)(ctx + bm0 * 4);
  const int4 cb = *(const int4*)(ctx + (bm0 + 16384) * 4);
#pragma unroll
  for (int h = 0; h < 2; ++h) {
    const int4 ix = h ? cb : ca;
    const int id[4] = {ix.x, ix.y, ix.z, ix.w};
    uint4 r[4][3];
#pragma unroll
    for (int k = 0; k < 4; ++k)
#pragma unroll
      for (int t = 0; t < 3; ++t)
        r[k][t] = *(const uint4*)(tabI + ((size_t)id[k] * 3 + t) * Ee + e);
    const int bm = bm0 + h * 16384;
#pragma unroll
    for (int t = 0; t < 3; ++t) {
      const unsigned int* p0 = (const unsigned int*)&r[0][t];
      const unsigned int* p1 = (const unsigned int*)&r[1][t];
      const unsigned int* p2 = (const unsigned int*)&r[2][t];
      const unsigned int* p3 = (const unsigned int*)&r[3][t];
      unsigned int o[4];
#pragma unroll
      for (int w = 0; w < 4; ++w) {
        // keep k-ascending left-assoc order (bit-identical to verified round-2 path)
        float lo = bf2f((unsigned short)(p0[w] & 0xffff)) + bf2f((unsigned short)(p1[w] & 0xffff)) +
                   bf2f((unsigned short)(p2[w] & 0xffff)) + bf2f((unsigned short)(p3[w] & 0xffff));
        float hi = bf2f((unsigned short)(p0[w] >> 16)) + bf2f((unsigned short)(p1[w] >> 16)) +
                   bf2f((unsigned short)(p2[w] >> 16)) + bf2f((unsigned short)(p3[w] >> 16));
        o[w] = f2bf(lo) | (f2bf(hi) << 16);
      }
      *(uint4*)(mem + t * MS + (size_t)bm * Ee + e) = *(uint4*)o;
    }
  }
}

// fallback: gather straight from fp32 tables (round-1 verified path)
__global__ void gather_mem_f32_kernel(const int* __restrict__ ctx,
                                      const float* __restrict__ A0,
                                      const float* __restrict__ A1,
                                      const float* __restrict__ A2,
                                      unsigned short* __restrict__ mem) {
  const int bm = blockIdx.x;
  const int t = blockIdx.y;
  const float* tab = (t == 0) ? A0 : (t == 1) ? A1 : A2;
  const int* c = ctx + bm * 4;
  const int i0 = c[0], i1 = c[1], i2 = c[2], i3 = c[3];
  const int e = threadIdx.x * 4;
  float4 s0 = *(const float4*)(tab + (size_t)i0 * Ee + e);
  float4 s1 = *(const float4*)(tab + (size_t)i1 * Ee + e);
  float4 s2 = *(const float4*)(tab + (size_t)i2 * Ee + e);
  float4 s3 = *(const float4*)(tab + (size_t)i3 * Ee + e);
  unsigned int o[2];
  o[0] = f2bf(s0.x + s1.x + s2.x + s3.x) | (f2bf(s0.y + s1.y + s2.y + s3.y) << 16);
  o[1] = f2bf(s0.z + s1.z + s2.z + s3.z) | (f2bf(s0.w + s1.w + s2.w + s3.w) << 16);
  *(uint2*)(mem + ((size_t)t * (Bb * Mm) + bm) * Ee + e) = *(uint2*)o;
}

// gi = A1[y_] @ W_ih^T (z=0), gh = h @ W_hh^T (z=1); fp32 tiled GEMM 64x64, BK=16
__global__ void gru_gemm_kernel(const int* __restrict__ y,
                                const float* __restrict__ A1,
                                const float* __restrict__ hprev,
                                const float* __restrict__ W_ih,
                                const float* __restrict__ W_hh,
                                float* __restrict__ gi,
                                float* __restrict__ gh) {
  const int z = blockIdx.z;
  const float* W = z ? W_hh : W_ih;     // [1536][512]
  float* C = z ? gh : gi;               // [256][1536]
  const int by = blockIdx.x * 64;
  const int jy = blockIdx.y * 64;
  __shared__ float As[16][65];
  __shared__ float Bs[16][65];
  const int tx = threadIdx.x & 15, ty = threadIdx.x >> 4;
  float acc[4][4] = {};
  for (int k0 = 0; k0 < Ee; k0 += 16) {
#pragma unroll
    for (int it = 0; it < 4; ++it) {
      int r = ty + it * 16;
      int row = by + r;
      const float* arow = z ? (hprev + (size_t)row * Ee) : (A1 + (size_t)y[row] * Ee);
      As[tx][r] = arow[k0 + tx];
      Bs[tx][r] = W[(size_t)(jy + r) * Ee + k0 + tx];
    }
    __syncthreads();
#pragma unroll
    for (int kk = 0; kk < 16; ++kk) {
      float a[4], bb[4];
#pragma unroll
      for (int i = 0; i < 4; ++i) { a[i] = As[kk][ty * 4 + i]; bb[i] = Bs[kk][tx * 4 + i]; }
#pragma unroll
      for (int i = 0; i < 4; ++i)
#pragma unroll
        for (int j = 0; j < 4; ++j)
          acc[i][j] += a[i] * bb[j];
    }
    __syncthreads();
  }
#pragma unroll
  for (int i = 0; i < 4; ++i)
#pragma unroll
    for (int j = 0; j < 4; ++j)
      C[(size_t)(by + ty * 4 + i) * E3 + jy + tx * 4 + j] = acc[i][j];
}

// Fused: GRU gates + all 3 hops. 256 blocks x 512 threads, 136KB dynamic LDS.
__global__ __launch_bounds__(512) void hop3_kernel(
    const unsigned short* __restrict__ mem,
    const float* __restrict__ gi, const float* __restrict__ gh,
    const float* __restrict__ b_ih, const float* __restrict__ b_hh,
    const float* __restrict__ h0,
    float* __restrict__ out_h, unsigned short* __restrict__ in2,
    float* __restrict__ p_out) {
  extern __shared__ char smem[];
  unsigned short* Vlds = (unsigned short*)smem;           // [128][512] bf16 = 128KB
  float* p_lds = (float*)(smem + 131072);                 // [128]
  float* qbuf = (float*)(smem + 131072 + 512);            // [512]
  float* obuf = (float*)(smem + 131072 + 512 + 2048);     // [2][512]

  const int b = blockIdx.x;
  const int tid = threadIdx.x;
  const int lane = tid & 63, w = tid >> 6;

  // ---- GRU gates: h_new -> out_h, in2[:,0:512], qbuf
  {
    const int e = tid;
    const float* gib = gi + (size_t)b * E3;
    const float* ghb = gh + (size_t)b * E3;
    float ir = gib[e] + b_ih[e];
    float iz = gib[512 + e] + b_ih[512 + e];
    float inn = gib[1024 + e] + b_ih[1024 + e];
    float hr = ghb[e] + b_hh[e];
    float hz = ghb[512 + e] + b_hh[512 + e];
    float hn = ghb[1024 + e] + b_hh[1024 + e];
    float r = 1.f / (1.f + __expf(-(ir + hr)));
    float z = 1.f / (1.f + __expf(-(iz + hz)));
    float n = tanhf(inn + r * hn);
    float hp = h0[(size_t)b * Ee + e];
    float hnew = (1.f - z) * n + z * hp;
    out_h[(size_t)b * Ee + e] = hnew;
    in2[(size_t)b * 1024 + e] = (unsigned short)f2bf(hnew);
    qbuf[e] = hnew;
  }
  __syncthreads();

  const unsigned short* mem0 = mem + (size_t)b * (Mm * Ee);
  const unsigned short* mem1 = mem + MS + (size_t)b * (Mm * Ee);
  const unsigned short* mem2 = mem + 2 * MS + (size_t)b * (Mm * Ee);

#define SCORE_PHASE(SRC_EXPR, EMIT)                                          \
  {                                                                          \
    float qf[8];                                                             \
    *(float4*)&qf[0] = *(const float4*)&qbuf[lane * 8];                      \
    *(float4*)&qf[4] = *(const float4*)&qbuf[lane * 8 + 4];                  \
    _Pragma("unroll")                                                        \
    for (int r = 0; r < 16; ++r) {                                           \
      const int m = w * 16 + r;                                              \
      uint4 kv = SRC_EXPR;                                                   \
      const unsigned int* p4 = (const unsigned int*)&kv;                     \
      float s = 0.f;                                                         \
      _Pragma("unroll")                                                      \
      for (int x = 0; x < 4; ++x) {                                          \
        s += bf2f((unsigned short)(p4[x] & 0xffff)) * qf[2 * x];             \
        s += bf2f((unsigned short)(p4[x] >> 16)) * qf[2 * x + 1];            \
      }                                                                      \
      _Pragma("unroll")                                                      \
      for (int off = 32; off > 0; off >>= 1) s += __shfl_down(s, off);       \
      if (lane == 0) { EMIT; }                                               \
    }                                                                        \
  }

#define SOFTMAX_PHASE                                                        \
  if (tid < 64) {                                                            \
    float v0 = p_lds[tid], v1 = p_lds[tid + 64];                             \
    float mx = fmaxf(v0, v1);                                                \
    _Pragma("unroll")                                                        \
    for (int off = 32; off > 0; off >>= 1) mx = fmaxf(mx, __shfl_xor(mx, off)); \
    float e0 = __expf(v0 - mx), e1 = __expf(v1 - mx);                        \
    float s = e0 + e1;                                                       \
    _Pragma("unroll")                                                        \
    for (int off = 32; off > 0; off >>= 1) s += __shfl_xor(s, off);          \
    float inv = 1.f / s;                                                     \
    p_lds[tid] = e0 * inv;                                                   \
    p_lds[tid + 64] = e1 * inv;                                              \
  }

#define O_PHASE(VSRC)                                                        \
  {                                                                          \
    const int g = tid >> 8, t = tid & 255;                                   \
    const int e2 = t * 2;                                                    \
    float a0 = 0.f, a1 = 0.f;                                                \
    _Pragma("unroll 4")                                                      \
    for (int m = g * 64; m < g * 64 + 64; ++m) {                             \
      unsigned int vv = *(const unsigned int*)(VSRC + (size_t)m * Ee + e2);  \
      *(unsigned int*)(Vlds + (size_t)m * Ee + e2) = vv;  /* tee for next K */ \
      float ww = p_lds[m];                                                   \
      a0 += ww * bf2f((unsigned short)(vv & 0xffff));                        \
      a1 += ww * bf2f((unsigned short)(vv >> 16));                           \
    }                                                                        \
    obuf[g * 512 + e2] = a0;                                                 \
    obuf[g * 512 + e2 + 1] = a1;                                             \
  }

  // ---- hop 0: scores vs mem0 (global)
  SCORE_PHASE(*(const uint4*)(mem0 + (size_t)m * Ee + lane * 8), p_lds[m] = s)
  __syncthreads();
  SOFTMAX_PHASE
  __syncthreads();
  O_PHASE(mem1)
  __syncthreads();
  {  // q += o ; in2 o-part
    const int e = tid;
    float o = obuf[e] + obuf[512 + e];
    qbuf[e] = qbuf[e] + o;
    in2[(size_t)b * 1024 + 512 + e] = (unsigned short)f2bf(o);
  }
  __syncthreads();

  // ---- hop 1: scores vs mem1 (now in LDS)
  SCORE_PHASE(*(const uint4*)(Vlds + (size_t)m * Ee + lane * 8), p_lds[m] = s)
  __syncthreads();
  SOFTMAX_PHASE
  __syncthreads();
  O_PHASE(mem2)
  __syncthreads();
  {
    const int e = tid;
    qbuf[e] = qbuf[e] + obuf[e] + obuf[512 + e];
  }
  __syncthreads();

  // ---- hop 2: raw scores vs mem2 (in LDS) -> p_out
  SCORE_PHASE(*(const uint4*)(Vlds + (size_t)m * Ee + lane * 8),
              p_out[b * Mm + m] = s)
}

// p_vocab = in2(bf16) @ lin_W^T + lin_b ; MFMA 16x16x32, tile 256x128, 512 thr
__global__ __launch_bounds__(512) void pvocab_kernel(
    const unsigned short* __restrict__ in2,
    const float* __restrict__ lin_W,
    const float* __restrict__ lin_b,
    float* __restrict__ out_pv) {
  const int v0 = blockIdx.x * 128;
  const int tid = threadIdx.x;
  const int lane = tid & 63, w = tid >> 6;
  const int wm = w >> 2, wn = w & 3;
  const int l15 = lane & 15, lg = lane >> 4;
  __shared__ __align__(16) unsigned short As[256][72];
  __shared__ __align__(16) unsigned short Ws[128][72];

  f32x4 acc[8][2];
#pragma unroll
  for (int i = 0; i < 8; ++i)
#pragma unroll
    for (int j = 0; j < 2; ++j)
      acc[i][j] = (f32x4){0.f, 0.f, 0.f, 0.f};

  for (int k0 = 0; k0 < 1024; k0 += 64) {
    {  // stage A: 256x64 bf16
      const int c = tid & 7, r0 = tid >> 3;
#pragma unroll
      for (int it = 0; it < 4; ++it) {
        int r = r0 + it * 64;
        *(uint4*)(&As[r][c * 8]) = *(const uint4*)(in2 + (size_t)r * 1024 + k0 + c * 8);
      }
    }
    {  // stage W: 128x64 fp32 -> bf16
      const int c = tid & 15, r0 = tid >> 4;
#pragma unroll
      for (int it = 0; it < 4; ++it) {
        int r = r0 + it * 32;
        float4 wv = *(const float4*)(lin_W + (size_t)(v0 + r) * 1024 + k0 + c * 4);
        unsigned int u0 = f2bf(wv.x) | (f2bf(wv.y) << 16);
        unsigned int u1 = f2bf(wv.z) | (f2bf(wv.w) << 16);
        *(uint2*)(&Ws[r][c * 4]) = make_uint2(u0, u1);
      }
    }
    __syncthreads();
#pragma unroll
    for (int kk = 0; kk < 2; ++kk) {
      bf16x8 wf[2];
#pragma unroll
      for (int j = 0; j < 2; ++j)
        wf[j] = *(const bf16x8*)(&Ws[wn * 32 + j * 16 + l15][kk * 32 + lg * 8]);
#pragma unroll
      for (int i = 0; i < 8; ++i) {
        bf16x8 af = *(const bf16x8*)(&As[wm * 128 + i * 16 + l15][kk * 32 + lg * 8]);
#pragma unroll
        for (int j = 0; j < 2; ++j)
          acc[i][j] = __builtin_amdgcn_mfma_f32_16x16x32_bf16(af, wf[j], acc[i][j], 0, 0, 0);
      }
    }
    __syncthreads();
  }

#pragma unroll
  for (int j = 0; j < 2; ++j) {
    int v = v0 + wn * 32 + j * 16 + l15;
    float bias = lin_b[v];
#pragma unroll
    for (int i = 0; i < 8; ++i) {
      int brow = wm * 128 + i * 16 + lg * 4;
#pragma unroll
      for (int rr = 0; rr < 4; ++rr)
        out_pv[(size_t)(brow + rr) * Vv + v] = acc[i][j][rr] + bias;
    }
  }
}

extern "C" void kernel_launch(void* const* d_in, const int* in_sizes, int n_in,
                              void* d_out, int out_size, void* d_ws, size_t ws_size,
                              hipStream_t stream) {
  const int* ctx = (const int*)d_in[0];
  const int* y = (const int*)d_in[1];
  const float* h0 = (const float*)d_in[2];
  const float* A0 = (const float*)d_in[3];
  const float* A1 = (const float*)d_in[4];
  const float* A2 = (const float*)d_in[5];
  // d_in[6] (C2) dead: memories[3] only feeds hop-2's o/q, which never reach an output
  const float* W_ih = (const float*)d_in[7];
  const float* W_hh = (const float*)d_in[8];
  const float* b_ih = (const float*)d_in[9];
  const float* b_hh = (const float*)d_in[10];
  const float* lin_W = (const float*)d_in[11];
  const float* lin_b = (const float*)d_in[12];

  const size_t tabBytes = (size_t)Vv * 3 * Ee * 2;   // 98.3 MB interleaved bf16 tables
  const size_t memBytes = 3 * MS * 2;                // 100.7 MB memories
  const size_t giBytes = (size_t)Bb * E3 * 4;
  const size_t in2Bytes = (size_t)Bb * 1024 * 2;
  const bool bf16path = ws_size >= tabBytes + memBytes + 2 * giBytes + in2Bytes;

  char* ws = (char*)d_ws;
  size_t off = 0;
  unsigned short* tabI = nullptr;
  if (bf16path) { tabI = (unsigned short*)ws; off += tabBytes; }
  unsigned short* mem = (unsigned short*)(ws + off); off += memBytes;
  float* gi = (float*)(ws + off); off += giBytes;
  float* gh = (float*)(ws + off); off += giBytes;
  unsigned short* in2 = (unsigned short*)(ws + off);

  float* out = (float*)d_out;
  float* p_ptr = out;                              // [B,M]
  float* p_voc = out + Bb * Mm;                    // [B,V]
  float* out_h = out + Bb * Mm + (size_t)Bb * Vv;  // [1,B,E]

  if (bf16path) {
    convert3_kernel<<<4096, 256, 0, stream>>>(A0, A1, A2, tabI);
    gather3_kernel<<<Bb * Mm / 2, 64, 0, stream>>>(ctx, tabI, mem);
  } else {
    gather_mem_f32_kernel<<<dim3(Bb * Mm, 3), 128, 0, stream>>>(ctx, A0, A1, A2, mem);
  }
  gru_gemm_kernel<<<dim3(4, 24, 2), 256, 0, stream>>>(y, A1, h0, W_ih, W_hh, gi, gh);
  hipFuncSetAttribute((const void*)hop3_kernel,
                      hipFuncAttributeMaxDynamicSharedMemorySize, 137728);
  hop3_kernel<<<Bb, 512, 137728, stream>>>(mem, gi, gh, b_ih, b_hh, h0, out_h, in2, p_ptr);
  pvocab_kernel<<<Vv / 128, 512, 0, stream>>>(in2, lin_W, lin_b, p_voc);
}